// Round 10
// baseline (5145.895 us; speedup 1.0000x reference)
//
#include <hip/hip_runtime.h>

// AdaptiveDownsampling: farthest point sampling (B=8, N=8192, m=4096) + gather.
// Outputs concatenated flat: dp [8,4096,3] then df [8,4096,256], float32.
//
// r2: np reference computes in float64 -> exact path must be fp64.
// r3-r5: register-array spill / AGPR tax lessons; named scalars only.
// r6: fp32 screen + rare exact fp64 path (sound: nonneg terms, margin 1e-4).
// r7: DPP wave max, 2 barriers + 2 LDS atomics: 4239 us (best so far).
// r9: redundant all-wave final reduce + 3 DPP chains -> issue-bound, 5024 us.
// r10: (1) ballot-gated outer branch around all 8 fp64 trigger blocks (the
//      flattened exec-masked fp64 bodies were ~300 cyc/iter of always-paid
//      issue); (2) tail v2: plain per-wave pair write -> barrier -> wave0-only
//      lex reduce + fused {coords,idx} 16B record -> barrier -> single
//      broadcast b128 read (replaces 2 atomics + 3 dependent LDS trips);
//      (3) owner/first-slot scan via 8 ballots + scalar cselect chain
//      (VALU -> scalar pipe). Exactness of every compare path unchanged.

typedef float v2f __attribute__((ext_vector_type(2)));

#define BATCH 8
#define NPTS  8192
#define MSEL  4096
#define NFEAT 256
#define BLOCK 1024

// fp64 square, opaque to the compiler so no v_fma_f64 contraction can merge
// the following adds (numpy float64 does separate mul / add / add).
__device__ __forceinline__ double sqd(double x) {
    double r;
    asm("v_mul_f64 %0, %1, %1" : "=v"(r) : "v"(x));
    return r;
}

// Exact 64-lane u32 max, VALU-only DPP (r7-verified), broadcast via lane 63.
__device__ __forceinline__ unsigned wave_umax(unsigned v) {
    unsigned t;
    t = (unsigned)__builtin_amdgcn_update_dpp(0, (int)v, 0x111, 0xf, 0xf, false); v = v > t ? v : t; // row_shr:1
    t = (unsigned)__builtin_amdgcn_update_dpp(0, (int)v, 0x112, 0xf, 0xf, false); v = v > t ? v : t; // row_shr:2
    t = (unsigned)__builtin_amdgcn_update_dpp(0, (int)v, 0x114, 0xf, 0xf, false); v = v > t ? v : t; // row_shr:4
    t = (unsigned)__builtin_amdgcn_update_dpp(0, (int)v, 0x118, 0xf, 0xf, false); v = v > t ? v : t; // row_shr:8
    t = (unsigned)__builtin_amdgcn_update_dpp(0, (int)v, 0x142, 0xf, 0xf, false); v = v > t ? v : t; // row_bcast:15
    t = (unsigned)__builtin_amdgcn_update_dpp(0, (int)v, 0x143, 0xf, 0xf, false); v = v > t ? v : t; // row_bcast:31
    return (unsigned)__builtin_amdgcn_readlane((int)v, 63);
}

// One lex-reduce stage over rows of 16 (r9-verified): take neighbor if its
// value is greater, or equal with smaller index. Invalid lanes inject
// (0,0,0xffffffff) which loses to any real entry. CTRL must be an ICE.
template <int CTRL>
__device__ __forceinline__ void lex_stage(unsigned& hi, unsigned& lo, unsigned& idx) {
    const unsigned ohi  = (unsigned)__builtin_amdgcn_update_dpp(0,  (int)hi,  CTRL, 0xf, 0xf, false);
    const unsigned olo  = (unsigned)__builtin_amdgcn_update_dpp(0,  (int)lo,  CTRL, 0xf, 0xf, false);
    const unsigned oidx = (unsigned)__builtin_amdgcn_update_dpp(-1, (int)idx, CTRL, 0xf, 0xf, false);
    const bool take = (ohi > hi) || (ohi == hi && ((olo > lo) || (olo == lo && oidx < idx)));
    hi  = take ? ohi  : hi;
    lo  = take ? olo  : lo;
    idx = take ? oidx : idx;
}

__launch_bounds__(BLOCK, 1)
__global__ void fps_kernel(const float* __restrict__ pts,   // [B, N, 3]
                           float* __restrict__ dp,          // [B, M, 3]
                           int* __restrict__ idx_out)       // [B, M]
{
    __shared__ float s_pts[NPTS * 3];     // 96 KB fp32 copy (winner broadcast)
    __shared__ ulonglong2 s_pair[16];     // per-wave {max_bits, first_idx}
    __shared__ float4 s_rec4;             // fused winner record {x,y,z,idx}

    const int b   = blockIdx.x;
    const int tid = threadIdx.x;
    const float* p = pts + (size_t)b * NPTS * 3;

    for (int i = tid; i < NPTS * 3; i += BLOCK) s_pts[i] = p[i];

    // Coords as float2 pairs (slots 2P, 2P+1) -> packed-fp32 screen.
#define DECLP(P, J0, J1) \
    v2f pxp##P = { p[(tid + J0 * 1024) * 3 + 0], p[(tid + J1 * 1024) * 3 + 0] }; \
    v2f pyp##P = { p[(tid + J0 * 1024) * 3 + 1], p[(tid + J1 * 1024) * 3 + 1] }; \
    v2f pzp##P = { p[(tid + J0 * 1024) * 3 + 2], p[(tid + J1 * 1024) * 3 + 2] };
    DECLP(0, 0, 1) DECLP(1, 2, 3) DECLP(2, 4, 5) DECLP(3, 6, 7)
#undef DECLP
    double mind0 = 1e10, mind1 = 1e10, mind2 = 1e10, mind3 = 1e10;
    double mind4 = 1e10, mind5 = 1e10, mind6 = 1e10, mind7 = 1e10;
    v2f mfmp0 = {1.0001e10f, 1.0001e10f}, mfmp1 = {1.0001e10f, 1.0001e10f};
    v2f mfmp2 = {1.0001e10f, 1.0001e10f}, mfmp3 = {1.0001e10f, 1.0001e10f};

    // Selection 0 is point 0 (deterministic start).
    float cx = p[0], cy = p[1], cz = p[2];
    if (tid == 0) {
        dp[(size_t)b * MSEL * 3 + 0] = cx;
        dp[(size_t)b * MSEL * 3 + 1] = cy;
        dp[(size_t)b * MSEL * 3 + 2] = cz;
        idx_out[b * MSEL + 0] = 0;
    }

    const int lane = tid & 63;
    const int wid  = tid >> 6;

    // Per-wave cached reduction result; every wave is dirty at k=1, which
    // initializes s_pair before its first read.
    unsigned long long wbits = 0ull;
    unsigned           widxw = 0xffffffffu;

    __syncthreads();   // s_pts visible

    for (int k = 1; k < MSEL; ++k) {
        const double cxd = (double)cx, cyd = (double)cy, czd = (double)cz;
        const v2f cx2 = {cx, cx}, cy2 = {cy, cy}, cz2 = {cz, cz};
        bool upd = false;

        // --- packed fp32 screen: slack e = d - mfm (e<0 <=> potential update) ---
        v2f e0, e1, e2, e3;
        {
            const v2f dx0 = pxp0 - cx2, dy0 = pyp0 - cy2, dz0 = pzp0 - cz2;
            const v2f dx1 = pxp1 - cx2, dy1 = pyp1 - cy2, dz1 = pzp1 - cz2;
            const v2f dx2 = pxp2 - cx2, dy2 = pyp2 - cy2, dz2 = pzp2 - cz2;
            const v2f dx3 = pxp3 - cx2, dy3 = pyp3 - cy2, dz3 = pzp3 - cz2;
            e0 = dx0 * dx0 + dy0 * dy0 + dz0 * dz0 - mfmp0;
            e1 = dx1 * dx1 + dy1 * dy1 + dz1 * dz1 - mfmp1;
            e2 = dx2 * dx2 + dy2 * dy2 + dz2 * dz2 - mfmp2;
            e3 = dx3 * dx3 + dy3 * dy3 + dz3 * dz3 - mfmp3;
        }
        const float mn = fminf(fminf(fminf(e0.x, e0.y), fminf(e1.x, e1.y)),
                               fminf(fminf(e2.x, e2.y), fminf(e3.x, e3.y)));

        // --- single wave-uniform gate around ALL fp64 trigger blocks ---
        if (__ballot(mn < 0.0f) != 0ull) {
#define EX64(PX, PY, PZ, MD, MF) { \
            const double ddx = (double)(PX) - cxd; \
            const double ddy = (double)(PY) - cyd; \
            const double ddz = (double)(PZ) - czd; \
            const double dd  = (sqd(ddx) + sqd(ddy)) + sqd(ddz); \
            if (dd < MD) { MD = dd; MF = (float)dd * 1.0001f; upd = true; } }
            if (e0.x < 0.0f) EX64(pxp0.x, pyp0.x, pzp0.x, mind0, mfmp0.x)
            if (e0.y < 0.0f) EX64(pxp0.y, pyp0.y, pzp0.y, mind1, mfmp0.y)
            if (e1.x < 0.0f) EX64(pxp1.x, pyp1.x, pzp1.x, mind2, mfmp1.x)
            if (e1.y < 0.0f) EX64(pxp1.y, pyp1.y, pzp1.y, mind3, mfmp1.y)
            if (e2.x < 0.0f) EX64(pxp2.x, pyp2.x, pzp2.x, mind4, mfmp2.x)
            if (e2.y < 0.0f) EX64(pxp2.y, pyp2.y, pzp2.y, mind5, mfmp2.y)
            if (e3.x < 0.0f) EX64(pxp3.x, pyp3.x, pzp3.x, mind6, mfmp3.x)
            if (e3.y < 0.0f) EX64(pxp3.y, pyp3.y, pzp3.y, mind7, mfmp3.y)
#undef EX64
        }

        // --- per-wave reduce, only if some lane updated (wave-uniform skip;
        //     the previous winner's wave always updates since its mind -> 0) ---
        const bool wdirty = (__ballot(upd) != 0ull);
        if (wdirty) {
            const double a0 = fmax(mind0, mind1), a1 = fmax(mind2, mind3);
            const double a2 = fmax(mind4, mind5), a3 = fmax(mind6, mind7);
            const double tbv = fmax(fmax(a0, a1), fmax(a2, a3));

            // wave max of nonneg double bits: two u32 DPP passes (exact)
            const unsigned long long tb = (unsigned long long)__double_as_longlong(tbv);
            const unsigned thi  = (unsigned)(tb >> 32);
            const unsigned hmax = wave_umax(thi);
            const unsigned lmax = wave_umax((thi == hmax) ? (unsigned)tb : 0u);
            wbits = ((unsigned long long)hmax << 32) | (unsigned long long)lmax;

            // first matching (slot, lane): 8 ballots + scalar-pipe scan.
            // Global idx = j*1024 + tid; j-stride (1024) dominates the 64-lane
            // span, so ascending j then ctz(lane) = min global idx in wave.
            const double wmax = __longlong_as_double((long long)wbits);
            const unsigned long long b0 = __ballot(mind0 == wmax);
            const unsigned long long b1 = __ballot(mind1 == wmax);
            const unsigned long long b2 = __ballot(mind2 == wmax);
            const unsigned long long b3 = __ballot(mind3 == wmax);
            const unsigned long long b4 = __ballot(mind4 == wmax);
            const unsigned long long b5 = __ballot(mind5 == wmax);
            const unsigned long long b6 = __ballot(mind6 == wmax);
            const unsigned long long b7 = __ballot(mind7 == wmax);
            unsigned long long bb = b7; unsigned jj = 7u;   // dirty wave => some owner
            if (b6) { bb = b6; jj = 6u; }
            if (b5) { bb = b5; jj = 5u; }
            if (b4) { bb = b4; jj = 4u; }
            if (b3) { bb = b3; jj = 3u; }
            if (b2) { bb = b2; jj = 2u; }
            if (b1) { bb = b1; jj = 1u; }
            if (b0) { bb = b0; jj = 0u; }
            widxw = (jj << 10) + (unsigned)(wid << 6) + (unsigned)__builtin_ctzll(bb);
        }
        // Plain write (no atomic). Race-free: wave0 reads s_pair strictly
        // between barriers A and B of iter k; any wave's next write happens
        // after it passes barrier B (which requires wave0's read to be done).
        if (wdirty && lane == 0)
            s_pair[wid] = (ulonglong2){wbits, (unsigned long long)widxw};
        __syncthreads();                                   // barrier A

        // --- wave 0 only: lex-reduce 16 pairs, fetch coords, fused record ---
        if (wid == 0) {
            const ulonglong2 pe = s_pair[lane & 15];
            unsigned hi  = (unsigned)(pe.x >> 32);
            unsigned lo  = (unsigned)pe.x;
            unsigned ix  = (unsigned)pe.y;
            lex_stage<0x111>(hi, lo, ix);   // row_shr:1
            lex_stage<0x112>(hi, lo, ix);   // row_shr:2
            lex_stage<0x114>(hi, lo, ix);   // row_shr:4
            lex_stage<0x118>(hi, lo, ix);   // row_shr:8 -> lane 15 complete
            const int w = __builtin_amdgcn_readlane((int)ix, 15);
            float val = __int_as_float(w);
            if (lane < 3) val = s_pts[w * 3 + lane];
            if (lane < 4) ((float*)&s_rec4)[lane] = val;
        }
        __syncthreads();                                   // barrier B

        // --- single broadcast b128 read: coords + idx in one LDS trip ---
        const float4 rc = s_rec4;
        cx = rc.x; cy = rc.y; cz = rc.z;
        if (tid == 0) {
            const int widx = __float_as_int(rc.w);
            idx_out[b * MSEL + k] = widx;
            float* o = dp + ((size_t)b * MSEL + k) * 3;
            o[0] = rc.x; o[1] = rc.y; o[2] = rc.z;
        }
    }
}

// One wave per selected row; lane i moves one float4 (64 * 16B = 1024B = full row).
__global__ void gather_kernel(const float* __restrict__ feats,  // [B, N, C]
                              const int* __restrict__ idx,      // [B, M]
                              float* __restrict__ df)           // [B, M, C]
{
    const int row  = blockIdx.x * 4 + (threadIdx.x >> 6);  // [0, B*M)
    const int lane = threadIdx.x & 63;
    const int b    = row >> 12;         // MSEL = 4096 rows per batch
    const int src  = idx[row];
    const float4* s = (const float4*)(feats + ((size_t)b * NPTS + src) * NFEAT);
    float4*       d = (float4*)(df + (size_t)row * NFEAT);
    d[lane] = s[lane];
}

extern "C" void kernel_launch(void* const* d_in, const int* in_sizes, int n_in,
                              void* d_out, int out_size, void* d_ws, size_t ws_size,
                              hipStream_t stream)
{
    const float* points   = (const float*)d_in[0];   // [8, 8192, 3]
    const float* features = (const float*)d_in[1];   // [8, 8192, 256]
    float* out = (float*)d_out;
    float* dp  = out;                                // [8, 4096, 3]
    float* df  = out + (size_t)BATCH * MSEL * 3;     // [8, 4096, 256]
    int*   idx_ws = (int*)d_ws;                      // [8, 4096] = 128 KB scratch

    fps_kernel<<<BATCH, BLOCK, 0, stream>>>(points, dp, idx_ws);
    gather_kernel<<<(BATCH * MSEL) / 4, 256, 0, stream>>>(features, idx_ws, df);
}